// Round 8
// baseline (449.557 us; speedup 1.0000x reference)
//
#include <hip/hip_runtime.h>
#include <stdint.h>

// ---------------------------------------------------------------------------
// VQ-VAE layer, all-bf16 MFMA pipeline.
// R15 -> R16: XCD remap bought ~nothing -- L3 (256MB) was already absorbing
// the cross-XCD A re-reads (GEMM never HBM-bound); dbuf ~neutral (implicit
// wave overlap already had it). GEMM is barrier-convoy-bound: 16 K-steps x
// per-step overheads that 4096-shape kernels amortize over 64 steps.
// R16 GEMM: BM 128->256 (8-wave 512-thr block, wave tile still 64x64):
//  - ONE barrier domain does 2x output per step; staging/unit-work 0.375x
//  - grid 256 = exactly 1 block/CU (LDS 96KB dbuf, launch_bounds(512,2))
//  - T3-minimum ordering explicit: STAGE(next) -> all-16 ds_reads ->
//    pure 32-MFMA block -> one barrier (R11-proven hoist; +64 VGPR < 256 cap)
// vq_dist: untouched (best-known R13 structure, ~174us).
// ---------------------------------------------------------------------------

typedef short bf16x8 __attribute__((ext_vector_type(8)));
typedef float f32x4 __attribute__((ext_vector_type(4)));

__device__ __forceinline__ void gl2lds16(const void* g, void* l) {
  __builtin_amdgcn_global_load_lds(
      (const __attribute__((address_space(1))) void*)g,
      (__attribute__((address_space(3))) void*)l, 16, 0, 0);
}

__device__ __forceinline__ float bf2f(unsigned short u) {
  return __uint_as_float(((unsigned)u) << 16);
}
__device__ __forceinline__ unsigned short f2bf(float f) {
  unsigned x = __float_as_uint(f);
  unsigned r = (x + 0x7fffu + ((x >> 16) & 1u)) >> 16;  // RNE
  return (unsigned short)r;
}
__device__ __forceinline__ unsigned long long packScore(float s, int code) {
  unsigned u = __float_as_uint(s);
  u = (u & 0x80000000u) ? ~u : (u | 0x80000000u);  // monotone map f32 -> u32
  return ((unsigned long long)u << 32) | (unsigned)code;
}
__device__ __forceinline__ unsigned long long shflxor_u64(unsigned long long v, int m) {
  union { unsigned long long u; int i[2]; } a;
  a.u = v;
  a.i[0] = __shfl_xor(a.i[0], m);
  a.i[1] = __shfl_xor(a.i[1], m);
  return a.u;
}

// ---------------------------------------------------------------------------
// cast fp32 -> bf16 (vectorized, n4 = count/4)
__global__ __launch_bounds__(256)
void cast_bf16(const float* __restrict__ X, unsigned short* __restrict__ Y, int n4) {
  int i = blockIdx.x * 256 + threadIdx.x;
  if (i < n4) {
    float4 v = ((const float4*)X)[i];
    ushort4 o = make_ushort4(f2bf(v.x), f2bf(v.y), f2bf(v.z), f2bf(v.w));
    ((ushort4*)Y)[i] = o;
  }
}

// transpose 1024x1024 fp32 W[i][j] -> bf16 Wt[j][i]
__global__ __launch_bounds__(256)
void transpose_cast(const float* __restrict__ W, unsigned short* __restrict__ Wt, int D) {
  __shared__ float s[32][33];
  int tx = threadIdx.x & 31, ty = threadIdx.x >> 5;  // 32x8
  int bx = blockIdx.x, by = blockIdx.y;
#pragma unroll
  for (int p = 0; p < 4; p++) {
    int r = by * 32 + ty + p * 8, c = bx * 32 + tx;
    s[ty + p * 8][tx] = W[(size_t)r * D + c];
  }
  __syncthreads();
#pragma unroll
  for (int p = 0; p < 4; p++) {
    int r = bx * 32 + ty + p * 8, c = by * 32 + tx;
    Wt[(size_t)r * D + c] = f2bf(s[tx][ty + p * 8]);
  }
}

// per-code squared norms (fp32), one wave per code row of 256
__global__ __launch_bounds__(256)
void code_norms(const float* __restrict__ cb, float* __restrict__ cn) {
  int row = blockIdx.x * 4 + (threadIdx.x >> 6);
  int lane = threadIdx.x & 63;
  float4 v = ((const float4*)(cb + (size_t)row * 256))[lane];
  float s = v.x * v.x + v.y * v.y + v.z * v.z + v.w * v.w;
#pragma unroll
  for (int off = 32; off > 0; off >>= 1) s += __shfl_down(s, off);
  if (lane == 0) cn[row] = s;
}

// ---------------------------------------------------------------------------
// GEMM: C[M,N] bf16 = relu(A[M,K]bf16 @ Bt[N,K]^T bf16 + bias)
// 256x128 tile, 8 waves (4M x 2N, 64x64 each), BK=64, dbuf DMA staging +
// XOR swizzle, XCD-chunked remap. One barrier per K-step; per step:
// STAGE(next) -> all-16 ds_reads -> pure 32-MFMA -> barrier.
// LDS 96KB -> exactly 1 block/CU; grid 256 = 1 per CU.
__global__ __launch_bounds__(512, 2)
void gemm_bias_relu(const unsigned short* __restrict__ A, const unsigned short* __restrict__ Bt,
                    const float* __restrict__ bias, unsigned short* __restrict__ C,
                    int M, int N, int K) {
  __shared__ unsigned short As[2][256 * 64];  // 2 x 32KB
  __shared__ unsigned short Bs[2][128 * 64];  // 2 x 16KB
  const int t = threadIdx.x;
  const int wv = t >> 6, lane = t & 63;
  const int wm = wv >> 1, wn = wv & 1;       // 4M x 2N wave grid
  const int quad = lane >> 4, l15 = lane & 15;

  // XCD-chunked bijective remap (nwg=256, cpx=32): XCD x gets a contiguous
  // row-panel range -> per-XCD working set ~4MB (A 2MB + B 2MB), L2-fit.
  const int lin = blockIdx.y * gridDim.x + blockIdx.x;
  const int cpx = (gridDim.x * gridDim.y) >> 3;
  const int nl = (lin & 7) * cpx + (lin >> 3);
  const int bx = nl % gridDim.x, by = nl / gridDim.x;
  const int row0 = by * 256, col0 = bx * 128;

  const int rsub = lane >> 3;            // row within 8-row slab
  const int dchunk = (lane & 7) ^ rsub;  // xor-swizzled data chunk to fetch

  f32x4 acc[4][4];
#pragma unroll
  for (int i = 0; i < 4; i++)
#pragma unroll
    for (int j = 0; j < 4; j++) acc[i][j] = (f32x4){0.f, 0.f, 0.f, 0.f};

  // prologue: stage k=0 into buffer 0.
  // A: 32 slabs of 8 rows; B: 16 slabs. wave wv stages A slabs {wv, wv+8,
  // wv+16, wv+24} and B slabs {wv, wv+8}.
#pragma unroll
  for (int j = 0; j < 4; j++) {
    int slab = j * 8 + wv;
    int row = slab * 8 + rsub;
    gl2lds16(A + (size_t)(row0 + row) * K + dchunk * 8, &As[0][slab * 512]);
  }
#pragma unroll
  for (int j = 0; j < 2; j++) {
    int slab = j * 8 + wv;
    int row = slab * 8 + rsub;
    gl2lds16(Bt + (size_t)(col0 + row) * K + dchunk * 8, &Bs[0][slab * 512]);
  }
  __syncthreads();

  int cur = 0;
  for (int k0 = 0; k0 < K; k0 += 64) {
    // STAGE next K-step first (T3-minimum order): DMA issue overlaps the
    // ds_read latency + MFMA; the end-of-step barrier drain lands late.
    if (k0 + 64 < K) {
#pragma unroll
      for (int j = 0; j < 4; j++) {
        int slab = j * 8 + wv;
        int row = slab * 8 + rsub;
        gl2lds16(A + (size_t)(row0 + row) * K + (k0 + 64) + dchunk * 8,
                 &As[cur ^ 1][slab * 512]);
      }
#pragma unroll
      for (int j = 0; j < 2; j++) {
        int slab = j * 8 + wv;
        int row = slab * 8 + rsub;
        gl2lds16(Bt + (size_t)(col0 + row) * K + (k0 + 64) + dchunk * 8,
                 &Bs[cur ^ 1][slab * 512]);
      }
    }
    // all 16 ds_reads up front (R11-proven hoist), then a pure MFMA block
    bf16x8 af[2][4], bfr[2][4];
#pragma unroll
    for (int kk = 0; kk < 2; kk++) {
#pragma unroll
      for (int mt = 0; mt < 4; mt++) {
        int row = wm * 64 + mt * 16 + l15;
        af[kk][mt] = *(const bf16x8*)(&As[cur][row * 64 + (((kk * 4 + quad) ^ (l15 & 7)) * 8)]);
      }
#pragma unroll
      for (int nt = 0; nt < 4; nt++) {
        int row = wn * 64 + nt * 16 + l15;
        bfr[kk][nt] = *(const bf16x8*)(&Bs[cur][row * 64 + (((kk * 4 + quad) ^ (l15 & 7)) * 8)]);
      }
    }
#pragma unroll
    for (int kk = 0; kk < 2; kk++)
#pragma unroll
      for (int mt = 0; mt < 4; mt++)
#pragma unroll
        for (int nt = 0; nt < 4; nt++)
          acc[mt][nt] = __builtin_amdgcn_mfma_f32_16x16x32_bf16(af[kk][mt], bfr[kk][nt], acc[mt][nt], 0, 0, 0);
    __syncthreads();
    cur ^= 1;
  }
#pragma unroll
  for (int mt = 0; mt < 4; mt++) {
#pragma unroll
    for (int nt = 0; nt < 4; nt++) {
      int col = col0 + wn * 64 + nt * 16 + l15;
      float b = bias[col];
#pragma unroll
      for (int r = 0; r < 4; r++) {
        int row = row0 + wm * 64 + mt * 16 + quad * 4 + r;
        float v = acc[mt][nt][r] + b;
        C[(size_t)row * N + col] = f2bf(v > 0.f ? v : 0.f);
      }
    }
  }
}

// ---------------------------------------------------------------------------
// LayerNorm over rows of 1024 (bf16 in); writes bf16 (obf) or fp32 (of32)
__global__ __launch_bounds__(256)
void ln_kernel(const unsigned short* __restrict__ X, const float* __restrict__ g,
               const float* __restrict__ b, unsigned short* __restrict__ obf,
               float* __restrict__ of32) {
  const int row = blockIdx.x, t = threadIdx.x;
  ushort4 u = ((const ushort4*)(X + (size_t)row * 1024))[t];
  float4 v = make_float4(bf2f(u.x), bf2f(u.y), bf2f(u.z), bf2f(u.w));
  float s = v.x + v.y + v.z + v.w;
  float ss = v.x * v.x + v.y * v.y + v.z * v.z + v.w * v.w;
#pragma unroll
  for (int off = 32; off > 0; off >>= 1) {
    s += __shfl_down(s, off);
    ss += __shfl_down(ss, off);
  }
  __shared__ float rs[4], rss[4];
  const int wave = t >> 6, lane = t & 63;
  if (lane == 0) { rs[wave] = s; rss[wave] = ss; }
  __syncthreads();
  float S = rs[0] + rs[1] + rs[2] + rs[3];
  float SS = rss[0] + rss[1] + rss[2] + rss[3];
  float m = S * (1.0f / 1024.0f);
  float var = SS * (1.0f / 1024.0f) - m * m;
  float rstd = 1.0f / sqrtf(var + 1e-5f);
  float4 gv = ((const float4*)g)[t];
  float4 bv = ((const float4*)b)[t];
  float4 o;
  o.x = (v.x - m) * rstd * gv.x + bv.x;
  o.y = (v.y - m) * rstd * gv.y + bv.y;
  o.z = (v.z - m) * rstd * gv.z + bv.z;
  o.w = (v.w - m) * rstd * gv.w + bv.w;
  if (obf) {
    ushort4 q = make_ushort4(f2bf(o.x), f2bf(o.y), f2bf(o.z), f2bf(o.w));
    ((ushort4*)(obf + (size_t)row * 1024))[t] = q;
  } else {
    ((float4*)(of32 + (size_t)row * 1024))[t] = o;
  }
}

// ---------------------------------------------------------------------------
// VQ distance+argmin+gather: Z[32768,256]bf16 vs Cb[8192,256]bf16.
// Block = 64 Z-rows x ALL 8192 codes (grid 512). Z register-resident zf[4][8].
// Chunk = 64 codes, ALL DMA-staged to LDS (dbuf 2x32KB, XOR swizzle,
// WAVE-PRIVATE slabs). NO barriers in main loop; per-wave vmcnt(0) at chunk
// top. R13 structure (best known): all-8 ds_reads at chunk top, deferred
// argmin under ds latency, pure 32-MFMA block, fused gather tail.
__global__ __launch_bounds__(256, 2)
void vq_dist(const unsigned short* __restrict__ Z, const unsigned short* __restrict__ Cb,
             const float* __restrict__ cnorm, const float* __restrict__ cbf,
             unsigned short* __restrict__ qb, int* __restrict__ counts,
             float* __restrict__ lpart) {
  __shared__ unsigned short Bs[2][64 * 256];  // 2 x 32KB
  __shared__ unsigned long long runmin[64];
  const int t = threadIdx.x;
  const int wv = t >> 6, lane = t & 63;
  const int quad = lane >> 4, l15 = lane & 15;
  const int row0 = blockIdx.x * 64;

  if (t < 64) runmin[t] = ~0ull;

  // Z fragments for this wave: rows mt*16+l15, K-step ks (8 bf16 each)
  bf16x8 zf[4][8];
#pragma unroll
  for (int mt = 0; mt < 4; mt++)
#pragma unroll
    for (int ks = 0; ks < 8; ks++)
      zf[mt][ks] = *(const bf16x8*)(Z + (size_t)(row0 + mt * 16 + l15) * 256 + ks * 32 + quad * 8);

  float msc[4][4];
  int mcd[4][4];
#pragma unroll
  for (int mt = 0; mt < 4; mt++)
#pragma unroll
    for (int r = 0; r < 4; r++) { msc[mt][r] = 3.4e38f; mcd[mt][r] = 0; }

  const int dcode = lane >> 5;  // 0/1 within slab
  const int dgr = lane & 31;    // 16B granule within code row
  const int slot = wv * 16 + l15;
  const int rxor = l15 & 7;

  // precomputed swizzled ds-read offsets (ushort units), slot folded in
  unsigned swz[8];
#pragma unroll
  for (int ks = 0; ks < 8; ks++)
    swz[ks] = (unsigned)slot * 256 + (unsigned)(((ks * 4 + quad) ^ rxor) * 8);

  // ---- prologue: stage chunk 0 into Bs[0]; cnorm for chunk 0 ----
#pragma unroll
  for (int j = 0; j < 8; j++) {
    int slab = wv * 8 + j;
    int sl = slab * 2 + dcode;
    gl2lds16(Cb + (size_t)sl * 256 + ((dgr ^ (sl & 7)) * 8), &Bs[0][slab * 512]);
  }
  float cn_old = 3.4e38f;       // sentinel: ch=-1 deferred argmin never wins
  float cn_new = cnorm[slot];   // chunk 0's norm for this lane's code

  f32x4 pacc[4];
#pragma unroll
  for (int mt = 0; mt < 4; mt++) pacc[mt] = (f32x4){0.f, 0.f, 0.f, 0.f};

  for (int ch = 0; ch < 128; ch++) {
    const int cur = ch & 1;
    // wait for THIS wave's outstanding vmem (incl. its DMA for chunk ch,
    // issued a full chunk ago, and the cnorm load); lgkm/exp not waited.
    __builtin_amdgcn_s_waitcnt(0x3F70);

    // prefetch DMA for chunk ch+1 (wrap: junk refill, never read)
    {
      const int cb2 = ((ch + 1) & 127) * 64;
#pragma unroll
      for (int j = 0; j < 8; j++) {
        int slab = wv * 8 + j;
        int sl = slab * 2 + dcode;
        gl2lds16(Cb + (size_t)(cb2 + sl) * 256 + ((dgr ^ (sl & 7)) * 8),
                 &Bs[cur ^ 1][slab * 512]);
      }
    }

    // issue ALL 8 ds_reads for this chunk
    const unsigned short* bsc = &Bs[cur][0];
    bf16x8 lbuf[8];
#pragma unroll
    for (int ks = 0; ks < 8; ks++)
      lbuf[ks] = *(const bf16x8*)(bsc + swz[ks]);

    // deferred argmin for chunk ch-1 under the ds latency.
    // Per-lane visit order ascending in ch -> strict < keeps lowest index.
    {
      int code = (ch - 1) * 64 + slot;
#pragma unroll
      for (int mt = 0; mt < 4; mt++)
#pragma unroll
        for (int r = 0; r < 4; r++) {
          float sc = cn_old - 2.0f * pacc[mt][r];
          if (sc < msc[mt][r]) { msc[mt][r] = sc; mcd[mt][r] = code; }
        }
    }
    cn_old = cn_new;
    cn_new = cnorm[(((ch + 1) & 127) * 64) + slot];

    // MFMA block
#pragma unroll
    for (int ks = 0; ks < 8; ks++) {
      if (ks == 0) {
        const f32x4 z4 = (f32x4){0.f, 0.f, 0.f, 0.f};
#pragma unroll
        for (int mt = 0; mt < 4; mt++)
          pacc[mt] = __builtin_amdgcn_mfma_f32_16x16x32_bf16(zf[mt][0], lbuf[0], z4, 0, 0, 0);
      } else {
#pragma unroll
        for (int mt = 0; mt < 4; mt++)
          pacc[mt] = __builtin_amdgcn_mfma_f32_16x16x32_bf16(zf[mt][ks], lbuf[ks], pacc[mt], 0, 0, 0);
      }
    }
  }
  // final deferred argmin (chunk 127)
  {
    int code = 127 * 64 + slot;
#pragma unroll
    for (int mt = 0; mt < 4; mt++)
#pragma unroll
      for (int r = 0; r < 4; r++) {
        float sc = cn_old - 2.0f * pacc[mt][r];
        if (sc < msc[mt][r]) { msc[mt][r] = sc; mcd[mt][r] = code; }
      }
  }

  __syncthreads();  // runmin init visible; all waves done before merge
#pragma unroll
  for (int mt = 0; mt < 4; mt++) {
#pragma unroll
    for (int r = 0; r < 4; r++) {
      unsigned long long bp = packScore(msc[mt][r], mcd[mt][r]);
#pragma unroll
      for (int m = 1; m < 16; m <<= 1) {
        unsigned long long o = shflxor_u64(bp, m);
        bp = o < bp ? o : bp;
      }
      if (l15 == 0) atomicMin(&runmin[mt * 16 + quad * 4 + r], bp);
    }
  }
  __syncthreads();

  // ---- tail: gather + qb write + loss partial + histogram ----
  float lp = 0.f;
#pragma unroll 4
  for (int rr = 0; rr < 16; rr++) {
    const int row = wv * 16 + rr;
    const int idx = (int)(runmin[row] & 0xFFFFFFFFull);
    float4 c = ((const float4*)(cbf + (size_t)idx * 256))[lane];
    ushort4 q = make_ushort4(f2bf(c.x), f2bf(c.y), f2bf(c.z), f2bf(c.w));
    ((ushort4*)(qb + (size_t)(row0 + row) * 256))[lane] = q;
    ushort4 z = ((const ushort4*)(Z + (size_t)(row0 + row) * 256))[lane];
    float dx = c.x - bf2f(z.x), dy = c.y - bf2f(z.y);
    float dz = c.z - bf2f(z.z), dw = c.w - bf2f(z.w);
    lp += dx * dx + dy * dy + dz * dz + dw * dw;
  }
  if (t < 64) atomicAdd(&counts[(int)(runmin[t] & 0xFFFFFFFFull)], 1);
#pragma unroll
  for (int off = 32; off > 0; off >>= 1) lp += __shfl_down(lp, off);
  __shared__ float sp[4];
  if (lane == 0) sp[wv] = lp;
  __syncthreads();
  if (t == 0) lpart[blockIdx.x] = sp[0] + sp[1] + sp[2] + sp[3];
}

// loss + perplexity scalars (lpart = 512 block partials)
__global__ __launch_bounds__(256)
void finalize(const int* __restrict__ counts, const float* __restrict__ lpart,
              float* __restrict__ out2) {
  const int t = threadIdx.x;
  double h = 0.0, l = 0.0;
  for (int i = t; i < 8192; i += 256) {
    double pr = (double)counts[i] * (1.0 / 32768.0);
    h += pr * log(pr + 1e-10);
  }
  for (int i = t; i < 512; i += 256) l += (double)lpart[i];
  __shared__ double sh[256], sl[256];
  sh[t] = h;
  sl[t] = l;
  __syncthreads();
  for (int w = 128; w > 0; w >>= 1) {
    if (t < w) { sh[t] += sh[t + w]; sl[t] += sl[t + w]; }
    __syncthreads();
  }
  if (t == 0) {
    out2[0] = (float)(1.25 * sl[0] * (1.0 / 8388608.0));
    out2[1] = (float)exp(-sh[0]);
  }
}

// ---------------------------------------------------------------------------
extern "C" void kernel_launch(void* const* d_in, const int* in_sizes, int n_in,
                              void* d_out, int out_size, void* d_ws, size_t ws_size,
                              hipStream_t stream) {
  const float* x = (const float*)d_in[0];
  const float* We1 = (const float*)d_in[1];
  const float* be1 = (const float*)d_in[2];
  const float* ge1 = (const float*)d_in[3];
  const float* bne1 = (const float*)d_in[4];
  const float* We2 = (const float*)d_in[5];
  const float* be2 = (const float*)d_in[6];
  const float* ge2 = (const float*)d_in[7];
  const float* bne2 = (const float*)d_in[8];
  const float* Wd1 = (const float*)d_in[9];
  const float* bd1 = (const float*)d_in[10];
  const float* gd1 = (const float*)d_in[11];
  const float* bnd1 = (const float*)d_in[12];
  const float* Wd2 = (const float*)d_in[13];
  const float* bd2 = (const float*)d_in[14];
  const float* gd2 = (const float*)d_in[15];
  const float* bnd2 = (const float*)d_in[16];
  const float* codebook = (const float*)d_in[17];
  float* out = (float*)d_out;

  char* w = (char*)d_ws;
  auto alloc = [&](size_t bytes) -> char* {
    char* p = w;
    w += (bytes + 255) & ~(size_t)255;
    return p;
  };
  unsigned short* xb = (unsigned short*)alloc((size_t)8192 * 1024 * 2);
  unsigned short* wt0 = (unsigned short*)alloc((size_t)1024 * 1024 * 2);
  unsigned short* wt1 = (unsigned short*)alloc((size_t)1024 * 1024 * 2);
  unsigned short* wt2 = (unsigned short*)alloc((size_t)1024 * 1024 * 2);
  unsigned short* wt3 = (unsigned short*)alloc((size_t)1024 * 1024 * 2);
  unsigned short* cbb = (unsigned short*)alloc((size_t)8192 * 256 * 2);
  float* cnorm = (float*)alloc((size_t)8192 * 4);
  unsigned short* act = (unsigned short*)alloc((size_t)8192 * 1024 * 2);
  unsigned short* yb = (unsigned short*)alloc((size_t)8192 * 1024 * 2);
  unsigned short* zb = (unsigned short*)alloc((size_t)8192 * 1024 * 2);
  unsigned short* qb = (unsigned short*)alloc((size_t)8192 * 1024 * 2);
  int* counts = (int*)alloc((size_t)8192 * 4);
  float* lpart = (float*)alloc((size_t)512 * 4);

  hipMemsetAsync(counts, 0, (size_t)8192 * 4, stream);

  cast_bf16<<<(2097152 + 255) / 256, 256, 0, stream>>>(x, xb, 2097152);
  dim3 tg(32, 32);
  transpose_cast<<<tg, 256, 0, stream>>>(We1, wt0, 1024);
  transpose_cast<<<tg, 256, 0, stream>>>(We2, wt1, 1024);
  transpose_cast<<<tg, 256, 0, stream>>>(Wd1, wt2, 1024);
  transpose_cast<<<tg, 256, 0, stream>>>(Wd2, wt3, 1024);
  cast_bf16<<<(524288 + 255) / 256, 256, 0, stream>>>(codebook, cbb, 524288);
  code_norms<<<2048, 256, 0, stream>>>(codebook, cnorm);

  dim3 gg(8, 32);  // 256 blocks of 512 threads (BM=256, BN=128)
  // encoder
  gemm_bias_relu<<<gg, 512, 0, stream>>>(xb, wt0, be1, act, 8192, 1024, 1024);
  ln_kernel<<<8192, 256, 0, stream>>>(act, ge1, bne1, yb, nullptr);
  gemm_bias_relu<<<gg, 512, 0, stream>>>(yb, wt1, be2, act, 8192, 1024, 1024);
  ln_kernel<<<8192, 256, 0, stream>>>(act, ge2, bne2, zb, nullptr);
  // VQ (distance + argmin + gather + histogram + loss partial, fused)
  vq_dist<<<512, 256, 0, stream>>>(zb, cbb, cnorm, codebook, qb, counts, lpart);
  // decoder
  gemm_bias_relu<<<gg, 512, 0, stream>>>(qb, wt2, bd1, act, 8192, 1024, 1024);
  ln_kernel<<<8192, 256, 0, stream>>>(act, gd1, bnd1, yb, nullptr);
  gemm_bias_relu<<<gg, 512, 0, stream>>>(yb, wt3, bd2, act, 8192, 1024, 1024);
  ln_kernel<<<8192, 256, 0, stream>>>(act, gd2, bnd2, nullptr, out);

  finalize<<<1, 256, 0, stream>>>(counts, lpart, out + 8388608);
}

// Round 9
// 428.211 us; speedup vs baseline: 1.0498x; 1.0498x over previous
//
#include <hip/hip_runtime.h>
#include <stdint.h>

// ---------------------------------------------------------------------------
// VQ-VAE layer, all-bf16 MFMA pipeline.
// R16 -> R17: BM=256 neutral -- third neutral GEMM restructure; conclusion:
// GEMM exec is ~35-40us each (near m97-structure ceiling for K=1024) and my
// earlier "228us GEMM pool" included ~50us of inter-dispatch gaps (17
// launches) plus LN/prep costs. R17 consolidates:
//  1. GEMM reverted to R15 (best: 128^2, dbuf, XCD remap).
//  2. ONE prep kernel replaces 7 dispatches (x-cast, 4 transposes, codebook
//     cast, code_norms + counts-zeroing folded in). 17 -> 11 dispatches.
//  3. LN: one wave per row (4 rows/block, grid 2048), pure shuffle reduce,
//     no LDS/barriers.
//  4. vq_dist untouched (R13 structure, ~174us).
// ---------------------------------------------------------------------------

typedef short bf16x8 __attribute__((ext_vector_type(8)));
typedef float f32x4 __attribute__((ext_vector_type(4)));

__device__ __forceinline__ void gl2lds16(const void* g, void* l) {
  __builtin_amdgcn_global_load_lds(
      (const __attribute__((address_space(1))) void*)g,
      (__attribute__((address_space(3))) void*)l, 16, 0, 0);
}

__device__ __forceinline__ float bf2f(unsigned short u) {
  return __uint_as_float(((unsigned)u) << 16);
}
__device__ __forceinline__ unsigned short f2bf(float f) {
  unsigned x = __float_as_uint(f);
  unsigned r = (x + 0x7fffu + ((x >> 16) & 1u)) >> 16;  // RNE
  return (unsigned short)r;
}
__device__ __forceinline__ unsigned long long packScore(float s, int code) {
  unsigned u = __float_as_uint(s);
  u = (u & 0x80000000u) ? ~u : (u | 0x80000000u);  // monotone map f32 -> u32
  return ((unsigned long long)u << 32) | (unsigned)code;
}
__device__ __forceinline__ unsigned long long shflxor_u64(unsigned long long v, int m) {
  union { unsigned long long u; int i[2]; } a;
  a.u = v;
  a.i[0] = __shfl_xor(a.i[0], m);
  a.i[1] = __shfl_xor(a.i[1], m);
  return a.u;
}

// ---------------------------------------------------------------------------
// prep: one kernel for all input conditioning.
//   blocks [0,2048)      : cast x fp32->bf16 (grid-stride x4)
//   blocks [2048,6144)   : 4x transpose+cast 1024^2 W -> bf16 W^T
//   blocks [6144,6656)   : cast codebook fp32->bf16 (grid-stride x4)
//   blocks [6656,8704)   : per-code norms (4 rows/block) + zero counts
__global__ __launch_bounds__(256)
void prep(const float* __restrict__ x, unsigned short* __restrict__ xb,
          const float* __restrict__ We1, const float* __restrict__ We2,
          const float* __restrict__ Wd1, const float* __restrict__ Wd2,
          unsigned short* __restrict__ wt0, unsigned short* __restrict__ wt1,
          unsigned short* __restrict__ wt2, unsigned short* __restrict__ wt3,
          const float* __restrict__ cb, unsigned short* __restrict__ cbb,
          float* __restrict__ cnorm, int* __restrict__ counts) {
  const int b = blockIdx.x;
  if (b < 2048) {
#pragma unroll
    for (int it = 0; it < 4; ++it) {
      int i = (it * 2048 + b) * 256 + threadIdx.x;
      float4 v = ((const float4*)x)[i];
      ((ushort4*)xb)[i] = make_ushort4(f2bf(v.x), f2bf(v.y), f2bf(v.z), f2bf(v.w));
    }
  } else if (b < 6144) {
    const int w = (b - 2048) >> 10;
    const int tile = (b - 2048) & 1023;
    const float* W = w == 0 ? We1 : w == 1 ? We2 : w == 2 ? Wd1 : Wd2;
    unsigned short* Wt = w == 0 ? wt0 : w == 1 ? wt1 : w == 2 ? wt2 : wt3;
    __shared__ float s[32][33];
    const int tx = threadIdx.x & 31, ty = threadIdx.x >> 5;
    const int bx = tile & 31, by = tile >> 5;
#pragma unroll
    for (int p = 0; p < 4; p++)
      s[ty + p * 8][tx] = W[(size_t)(by * 32 + ty + p * 8) * 1024 + bx * 32 + tx];
    __syncthreads();
#pragma unroll
    for (int p = 0; p < 4; p++)
      Wt[(size_t)(bx * 32 + ty + p * 8) * 1024 + by * 32 + tx] = f2bf(s[tx][ty + p * 8]);
  } else if (b < 6656) {
    const int bb = b - 6144;
#pragma unroll
    for (int it = 0; it < 4; ++it) {
      int i = (it * 512 + bb) * 256 + threadIdx.x;
      float4 v = ((const float4*)cb)[i];
      ((ushort4*)cbb)[i] = make_ushort4(f2bf(v.x), f2bf(v.y), f2bf(v.z), f2bf(v.w));
    }
  } else {
    const int row = (b - 6656) * 4 + (threadIdx.x >> 6);
    const int lane = threadIdx.x & 63;
    float4 v = ((const float4*)(cb + (size_t)row * 256))[lane];
    float s = v.x * v.x + v.y * v.y + v.z * v.z + v.w * v.w;
#pragma unroll
    for (int off = 32; off > 0; off >>= 1) s += __shfl_down(s, off);
    if (lane == 0) {
      cnorm[row] = s;
      counts[row] = 0;  // replaces the memset dispatch
    }
  }
}

// ---------------------------------------------------------------------------
// GEMM: C[M,N] bf16 = relu(A[M,K]bf16 @ Bt[N,K]^T bf16 + bias)
// 128x128 tile, BK=64, double-buffered DMA staging + XOR swizzle,
// XCD-chunked block remap (R15 config -- best known).
__global__ __launch_bounds__(256, 2)
void gemm_bias_relu(const unsigned short* __restrict__ A, const unsigned short* __restrict__ Bt,
                    const float* __restrict__ bias, unsigned short* __restrict__ C,
                    int M, int N, int K) {
  __shared__ unsigned short As[2][128 * 64];
  __shared__ unsigned short Bs[2][128 * 64];
  const int t = threadIdx.x;
  const int wv = t >> 6, lane = t & 63;
  const int wm = wv >> 1, wn = wv & 1;
  const int quad = lane >> 4, l15 = lane & 15;

  const int lin = blockIdx.y * gridDim.x + blockIdx.x;
  const int cpx = (gridDim.x * gridDim.y) >> 3;
  const int nl = (lin & 7) * cpx + (lin >> 3);
  const int bx = nl % gridDim.x, by = nl / gridDim.x;
  const int row0 = by * 128, col0 = bx * 128;

  const int rsub = lane >> 3;            // row within 8-row slab
  const int dchunk = (lane & 7) ^ rsub;  // xor-swizzled data chunk to fetch

  f32x4 acc[4][4];
#pragma unroll
  for (int i = 0; i < 4; i++)
#pragma unroll
    for (int j = 0; j < 4; j++) acc[i][j] = (f32x4){0.f, 0.f, 0.f, 0.f};

  // prologue: stage k=0 into buffer 0
#pragma unroll
  for (int j = 0; j < 4; j++) {
    int slab = j * 4 + wv;
    int row = slab * 8 + rsub;
    gl2lds16(A + (size_t)(row0 + row) * K + dchunk * 8, &As[0][slab * 512]);
    gl2lds16(Bt + (size_t)(col0 + row) * K + dchunk * 8, &Bs[0][slab * 512]);
  }
  __syncthreads();

  int cur = 0;
  for (int k0 = 0; k0 < K; k0 += 64) {
    if (k0 + 64 < K) {
#pragma unroll
      for (int j = 0; j < 4; j++) {
        int slab = j * 4 + wv;
        int row = slab * 8 + rsub;
        gl2lds16(A + (size_t)(row0 + row) * K + (k0 + 64) + dchunk * 8,
                 &As[cur ^ 1][slab * 512]);
        gl2lds16(Bt + (size_t)(col0 + row) * K + (k0 + 64) + dchunk * 8,
                 &Bs[cur ^ 1][slab * 512]);
      }
    }
#pragma unroll
    for (int kk = 0; kk < 2; kk++) {
      bf16x8 af[4], bfr[4];
#pragma unroll
      for (int mt = 0; mt < 4; mt++) {
        int row = wm * 64 + mt * 16 + l15;
        af[mt] = *(const bf16x8*)(&As[cur][row * 64 + (((kk * 4 + quad) ^ (l15 & 7)) * 8)]);
      }
#pragma unroll
      for (int nt = 0; nt < 4; nt++) {
        int row = wn * 64 + nt * 16 + l15;
        bfr[nt] = *(const bf16x8*)(&Bs[cur][row * 64 + (((kk * 4 + quad) ^ (l15 & 7)) * 8)]);
      }
#pragma unroll
      for (int mt = 0; mt < 4; mt++)
#pragma unroll
        for (int nt = 0; nt < 4; nt++)
          acc[mt][nt] = __builtin_amdgcn_mfma_f32_16x16x32_bf16(af[mt], bfr[nt], acc[mt][nt], 0, 0, 0);
    }
    __syncthreads();
    cur ^= 1;
  }
#pragma unroll
  for (int mt = 0; mt < 4; mt++) {
#pragma unroll
    for (int nt = 0; nt < 4; nt++) {
      int col = col0 + wn * 64 + nt * 16 + l15;
      float b = bias[col];
#pragma unroll
      for (int r = 0; r < 4; r++) {
        int row = row0 + wm * 64 + mt * 16 + quad * 4 + r;
        float v = acc[mt][nt][r] + b;
        C[(size_t)row * N + col] = f2bf(v > 0.f ? v : 0.f);
      }
    }
  }
}

// ---------------------------------------------------------------------------
// LayerNorm, one WAVE per row of 1024 (4 rows per 256-thr block).
// Pure shuffle reduction -- no LDS, no barriers. Writes bf16 (obf) or fp32.
__global__ __launch_bounds__(256)
void ln_kernel(const unsigned short* __restrict__ X, const float* __restrict__ g,
               const float* __restrict__ b, unsigned short* __restrict__ obf,
               float* __restrict__ of32) {
  const int wave = threadIdx.x >> 6, lane = threadIdx.x & 63;
  const int row = blockIdx.x * 4 + wave;
  const unsigned short* xr = X + (size_t)row * 1024;
  bf16x8 u0 = *(const bf16x8*)(xr + lane * 8);
  bf16x8 u1 = *(const bf16x8*)(xr + 512 + lane * 8);
  float v0[8], v1[8];
  float s = 0.f, ss = 0.f;
#pragma unroll
  for (int i = 0; i < 8; i++) {
    v0[i] = bf2f((unsigned short)u0[i]);
    v1[i] = bf2f((unsigned short)u1[i]);
    s += v0[i] + v1[i];
    ss += v0[i] * v0[i] + v1[i] * v1[i];
  }
#pragma unroll
  for (int off = 32; off > 0; off >>= 1) {
    s += __shfl_down(s, off);
    ss += __shfl_down(ss, off);
  }
  s = __shfl(s, 0);
  ss = __shfl(ss, 0);
  const float m = s * (1.0f / 1024.0f);
  const float var = ss * (1.0f / 1024.0f) - m * m;
  const float rstd = 1.0f / sqrtf(var + 1e-5f);
  const int c0 = lane * 8;
  float4 ga = *(const float4*)(g + c0), gb4 = *(const float4*)(g + c0 + 4);
  float4 gc = *(const float4*)(g + 512 + c0), gd = *(const float4*)(g + 512 + c0 + 4);
  float4 ba = *(const float4*)(b + c0), bb4 = *(const float4*)(b + c0 + 4);
  float4 bc = *(const float4*)(b + 512 + c0), bd = *(const float4*)(b + 512 + c0 + 4);
  float o0[8], o1[8];
  const float* gl0 = &ga.x; const float* gl1 = &gc.x;  // [ga|gb4], [gc|gd] contiguous
  float gv0[8] = {ga.x, ga.y, ga.z, ga.w, gb4.x, gb4.y, gb4.z, gb4.w};
  float gv1[8] = {gc.x, gc.y, gc.z, gc.w, gd.x, gd.y, gd.z, gd.w};
  float bv0[8] = {ba.x, ba.y, ba.z, ba.w, bb4.x, bb4.y, bb4.z, bb4.w};
  float bv1[8] = {bc.x, bc.y, bc.z, bc.w, bd.x, bd.y, bd.z, bd.w};
  (void)gl0; (void)gl1;
#pragma unroll
  for (int i = 0; i < 8; i++) {
    o0[i] = (v0[i] - m) * rstd * gv0[i] + bv0[i];
    o1[i] = (v1[i] - m) * rstd * gv1[i] + bv1[i];
  }
  if (obf) {
    bf16x8 q0, q1;
#pragma unroll
    for (int i = 0; i < 8; i++) { q0[i] = (short)f2bf(o0[i]); q1[i] = (short)f2bf(o1[i]); }
    *(bf16x8*)(obf + (size_t)row * 1024 + c0) = q0;
    *(bf16x8*)(obf + (size_t)row * 1024 + 512 + c0) = q1;
  } else {
    float* orow = of32 + (size_t)row * 1024;
    *(float4*)(orow + c0) = make_float4(o0[0], o0[1], o0[2], o0[3]);
    *(float4*)(orow + c0 + 4) = make_float4(o0[4], o0[5], o0[6], o0[7]);
    *(float4*)(orow + 512 + c0) = make_float4(o1[0], o1[1], o1[2], o1[3]);
    *(float4*)(orow + 512 + c0 + 4) = make_float4(o1[4], o1[5], o1[6], o1[7]);
  }
}

// ---------------------------------------------------------------------------
// VQ distance+argmin+gather: Z[32768,256]bf16 vs Cb[8192,256]bf16.
// R13 structure (best known) -- see prior rounds for derivation.
__global__ __launch_bounds__(256, 2)
void vq_dist(const unsigned short* __restrict__ Z, const unsigned short* __restrict__ Cb,
             const float* __restrict__ cnorm, const float* __restrict__ cbf,
             unsigned short* __restrict__ qb, int* __restrict__ counts,
             float* __restrict__ lpart) {
  __shared__ unsigned short Bs[2][64 * 256];  // 2 x 32KB
  __shared__ unsigned long long runmin[64];
  const int t = threadIdx.x;
  const int wv = t >> 6, lane = t & 63;
  const int quad = lane >> 4, l15 = lane & 15;
  const int row0 = blockIdx.x * 64;

  if (t < 64) runmin[t] = ~0ull;

  bf16x8 zf[4][8];
#pragma unroll
  for (int mt = 0; mt < 4; mt++)
#pragma unroll
    for (int ks = 0; ks < 8; ks++)
      zf[mt][ks] = *(const bf16x8*)(Z + (size_t)(row0 + mt * 16 + l15) * 256 + ks * 32 + quad * 8);

  float msc[4][4];
  int mcd[4][4];
#pragma unroll
  for (int mt = 0; mt < 4; mt++)
#pragma unroll
    for (int r = 0; r < 4; r++) { msc[mt][r] = 3.4e38f; mcd[mt][r] = 0; }

  const int dcode = lane >> 5;
  const int dgr = lane & 31;
  const int slot = wv * 16 + l15;
  const int rxor = l15 & 7;

  unsigned swz[8];
#pragma unroll
  for (int ks = 0; ks < 8; ks++)
    swz[ks] = (unsigned)slot * 256 + (unsigned)(((ks * 4 + quad) ^ rxor) * 8);

#pragma unroll
  for (int j = 0; j < 8; j++) {
    int slab = wv * 8 + j;
    int sl = slab * 2 + dcode;
    gl2lds16(Cb + (size_t)sl * 256 + ((dgr ^ (sl & 7)) * 8), &Bs[0][slab * 512]);
  }
  float cn_old = 3.4e38f;
  float cn_new = cnorm[slot];

  f32x4 pacc[4];
#pragma unroll
  for (int mt = 0; mt < 4; mt++) pacc[mt] = (f32x4){0.f, 0.f, 0.f, 0.f};

  for (int ch = 0; ch < 128; ch++) {
    const int cur = ch & 1;
    __builtin_amdgcn_s_waitcnt(0x3F70);

    {
      const int cb2 = ((ch + 1) & 127) * 64;
#pragma unroll
      for (int j = 0; j < 8; j++) {
        int slab = wv * 8 + j;
        int sl = slab * 2 + dcode;
        gl2lds16(Cb + (size_t)(cb2 + sl) * 256 + ((dgr ^ (sl & 7)) * 8),
                 &Bs[cur ^ 1][slab * 512]);
      }
    }

    const unsigned short* bsc = &Bs[cur][0];
    bf16x8 lbuf[8];
#pragma unroll
    for (int ks = 0; ks < 8; ks++)
      lbuf[ks] = *(const bf16x8*)(bsc + swz[ks]);

    {
      int code = (ch - 1) * 64 + slot;
#pragma unroll
      for (int mt = 0; mt < 4; mt++)
#pragma unroll
        for (int r = 0; r < 4; r++) {
          float sc = cn_old - 2.0f * pacc[mt][r];
          if (sc < msc[mt][r]) { msc[mt][r] = sc; mcd[mt][r] = code; }
        }
    }
    cn_old = cn_new;
    cn_new = cnorm[(((ch + 1) & 127) * 64) + slot];

#pragma unroll
    for (int ks = 0; ks < 8; ks++) {
      if (ks == 0) {
        const f32x4 z4 = (f32x4){0.f, 0.f, 0.f, 0.f};
#pragma unroll
        for (int mt = 0; mt < 4; mt++)
          pacc[mt] = __builtin_amdgcn_mfma_f32_16x16x32_bf16(zf[mt][0], lbuf[0], z4, 0, 0, 0);
      } else {
#pragma unroll
        for (int mt = 0; mt < 4; mt++)
          pacc[mt] = __builtin_amdgcn_mfma_f32_16x16x32_bf16(zf[mt][ks], lbuf[ks], pacc[mt], 0, 0, 0);
      }
    }
  }
  {
    int code = 127 * 64 + slot;
#pragma unroll
    for (int mt = 0; mt < 4; mt++)
#pragma unroll
      for (int r = 0; r < 4; r++) {
        float sc = cn_old - 2.0f * pacc[mt][r];
        if (sc < msc[mt][r]) { msc[mt][r] = sc; mcd[mt][r] = code; }
      }
  }

  __syncthreads();
#pragma unroll
  for (int mt = 0; mt < 4; mt++) {
#pragma unroll
    for (int r = 0; r < 4; r++) {
      unsigned long long bp = packScore(msc[mt][r], mcd[mt][r]);
#pragma unroll
      for (int m = 1; m < 16; m <<= 1) {
        unsigned long long o = shflxor_u64(bp, m);
        bp = o < bp ? o : bp;
      }
      if (l15 == 0) atomicMin(&runmin[mt * 16 + quad * 4 + r], bp);
    }
  }
  __syncthreads();

  float lp = 0.f;
#pragma unroll 4
  for (int rr = 0; rr < 16; rr++) {
    const int row = wv * 16 + rr;
    const int idx = (int)(runmin[row] & 0xFFFFFFFFull);
    float4 c = ((const float4*)(cbf + (size_t)idx * 256))[lane];
    ushort4 q = make_ushort4(f2bf(c.x), f2bf(c.y), f2bf(c.z), f2bf(c.w));
    ((ushort4*)(qb + (size_t)(row0 + row) * 256))[lane] = q;
    ushort4 z = ((const ushort4*)(Z + (size_t)(row0 + row) * 256))[lane];
    float dx = c.x - bf2f(z.x), dy = c.y - bf2f(z.y);
    float dz = c.z - bf2f(z.z), dw = c.w - bf2f(z.w);
    lp += dx * dx + dy * dy + dz * dz + dw * dw;
  }
  if (t < 64) atomicAdd(&counts[(int)(runmin[t] & 0xFFFFFFFFull)], 1);
#pragma unroll
  for (int off = 32; off > 0; off >>= 1) lp += __shfl_down(lp, off);
  __shared__ float sp[4];
  if (lane == 0) sp[wv] = lp;
  __syncthreads();
  if (t == 0) lpart[blockIdx.x] = sp[0] + sp[1] + sp[2] + sp[3];
}

// loss + perplexity scalars (lpart = 512 block partials)
__global__ __launch_bounds__(256)
void finalize(const int* __restrict__ counts, const float* __restrict__ lpart,
              float* __restrict__ out2) {
  const int t = threadIdx.x;
  double h = 0.0, l = 0.0;
  for (int i = t; i < 8192; i += 256) {
    double pr = (double)counts[i] * (1.0 / 32768.0);
    h += pr * log(pr + 1e-10);
  }
  for (int i = t; i < 512; i += 256) l += (double)lpart[i];
  __shared__ double sh[256], sl[256];
  sh[t] = h;
  sl[t] = l;
  __syncthreads();
  for (int w = 128; w > 0; w >>= 1) {
    if (t < w) { sh[t] += sh[t + w]; sl[t] += sl[t + w]; }
    __syncthreads();
  }
  if (t == 0) {
    out2[0] = (float)(1.25 * sl[0] * (1.0 / 8388608.0));
    out2[1] = (float)exp(-sh[0]);
  }
}

// ---------------------------------------------------------------------------
extern "C" void kernel_launch(void* const* d_in, const int* in_sizes, int n_in,
                              void* d_out, int out_size, void* d_ws, size_t ws_size,
                              hipStream_t stream) {
  const float* x = (const float*)d_in[0];
  const float* We1 = (const float*)d_in[1];
  const float* be1 = (const float*)d_in[2];
  const float* ge1 = (const float*)d_in[3];
  const float* bne1 = (const float*)d_in[4];
  const float* We2 = (const float*)d_in[5];
  const float* be2 = (const float*)d_in[6];
  const float* ge2 = (const float*)d_in[7];
  const float* bne2 = (const float*)d_in[8];
  const float* Wd1 = (const float*)d_in[9];
  const float* bd1 = (const float*)d_in[10];
  const float* gd1 = (const float*)d_in[11];
  const float* bnd1 = (const float*)d_in[12];
  const float* Wd2 = (const float*)d_in[13];
  const float* bd2 = (const float*)d_in[14];
  const float* gd2 = (const float*)d_in[15];
  const float* bnd2 = (const float*)d_in[16];
  const float* codebook = (const float*)d_in[17];
  float* out = (float*)d_out;

  char* w = (char*)d_ws;
  auto alloc = [&](size_t bytes) -> char* {
    char* p = w;
    w += (bytes + 255) & ~(size_t)255;
    return p;
  };
  unsigned short* xb = (unsigned short*)alloc((size_t)8192 * 1024 * 2);
  unsigned short* wt0 = (unsigned short*)alloc((size_t)1024 * 1024 * 2);
  unsigned short* wt1 = (unsigned short*)alloc((size_t)1024 * 1024 * 2);
  unsigned short* wt2 = (unsigned short*)alloc((size_t)1024 * 1024 * 2);
  unsigned short* wt3 = (unsigned short*)alloc((size_t)1024 * 1024 * 2);
  unsigned short* cbb = (unsigned short*)alloc((size_t)8192 * 256 * 2);
  float* cnorm = (float*)alloc((size_t)8192 * 4);
  unsigned short* act = (unsigned short*)alloc((size_t)8192 * 1024 * 2);
  unsigned short* yb = (unsigned short*)alloc((size_t)8192 * 1024 * 2);
  unsigned short* zb = (unsigned short*)alloc((size_t)8192 * 1024 * 2);
  unsigned short* qb = (unsigned short*)alloc((size_t)8192 * 1024 * 2);
  int* counts = (int*)alloc((size_t)8192 * 4);
  float* lpart = (float*)alloc((size_t)512 * 4);

  // all input conditioning in one dispatch (memset folded into norms section)
  prep<<<8704, 256, 0, stream>>>(x, xb, We1, We2, Wd1, Wd2, wt0, wt1, wt2, wt3,
                                 codebook, cbb, cnorm, counts);

  dim3 gg(8, 64);
  // encoder
  gemm_bias_relu<<<gg, 256, 0, stream>>>(xb, wt0, be1, act, 8192, 1024, 1024);
  ln_kernel<<<2048, 256, 0, stream>>>(act, ge1, bne1, yb, nullptr);
  gemm_bias_relu<<<gg, 256, 0, stream>>>(yb, wt1, be2, act, 8192, 1024, 1024);
  ln_kernel<<<2048, 256, 0, stream>>>(act, ge2, bne2, zb, nullptr);
  // VQ (distance + argmin + gather + histogram + loss partial, fused)
  vq_dist<<<512, 256, 0, stream>>>(zb, cbb, cnorm, codebook, qb, counts, lpart);
  // decoder
  gemm_bias_relu<<<gg, 256, 0, stream>>>(qb, wt2, bd1, act, 8192, 1024, 1024);
  ln_kernel<<<2048, 256, 0, stream>>>(act, gd1, bnd1, yb, nullptr);
  gemm_bias_relu<<<gg, 256, 0, stream>>>(yb, wt3, bd2, act, 8192, 1024, 1024);
  ln_kernel<<<2048, 256, 0, stream>>>(act, gd2, bnd2, nullptr, out);

  finalize<<<1, 256, 0, stream>>>(counts, lpart, out + 8388608);
}